// Round 1
// baseline (673.231 us; speedup 1.0000x reference)
//
#include <hip/hip_runtime.h>
#include <math.h>

#define B_    16
#define N_    8192
#define D_    256
#define BN_   32
#define R_    4
#define LOGN  13

// ---------------------------------------------------------------------------
// Morton helpers (exact replica of reference bit-interleave)
// ---------------------------------------------------------------------------
__device__ __forceinline__ unsigned long long interleave3(unsigned long long v) {
    v = v & 2097151ULL;
    v = v | (v << 32);
    v = v & 8725724278095871ULL;
    v = v | ((v << 16) & 8725728556220671ULL);
    v = v | ((v << 8)  & 282506020581391ULL);
    v = v | ((v << 4)  & 294878547030211ULL);
    v = v | ((v << 2)  & 321685687669321ULL);
    return v;
}

__device__ __forceinline__ long long quant10(float c) {
    long long v = (long long)(c * 1023.0f);   // trunc toward zero, matches astype(int64)
    v = v < 0 ? 0 : (v > 1023 ? 1023 : v);
    return v;
}

// ---------------------------------------------------------------------------
// K1: per-batch stable argsort of morton keys via bitonic sort in LDS.
// key = (morton << 13) | index  -> stable tie-break identical to jnp.argsort.
// ---------------------------------------------------------------------------
__global__ void sort_kernel(const float* __restrict__ coords, int* __restrict__ order) {
    extern __shared__ unsigned long long skey[];    // 8192 * 8B = 64 KB
    const int b = blockIdx.x;
    const int t = threadIdx.x;

    for (int i = t; i < N_; i += 256) {
        const float* c = coords + ((size_t)b * N_ + i) * 3;
        unsigned long long mx = interleave3((unsigned long long)quant10(c[0]));
        unsigned long long my = interleave3((unsigned long long)quant10(c[1]));
        unsigned long long mz = interleave3((unsigned long long)quant10(c[2]));
        unsigned long long m = mx | (my << 1) | (mz << 2);
        skey[i] = (m << LOGN) | (unsigned long long)i;
    }
    __syncthreads();

    for (int size = 2; size <= N_; size <<= 1) {
        for (int stride = size >> 1; stride > 0; stride >>= 1) {
            for (int i = t; i < N_; i += 256) {
                int l = i ^ stride;
                if (l > i) {
                    unsigned long long a = skey[i], c2 = skey[l];
                    bool up = ((i & size) == 0);
                    if ((a > c2) == up) { skey[i] = c2; skey[l] = a; }
                }
            }
            __syncthreads();
        }
    }
    for (int i = t; i < N_; i += 256)
        order[b * N_ + i] = (int)(skey[i] & (unsigned long long)(N_ - 1));
}

// ---------------------------------------------------------------------------
// K2: z[b,n,k] = relu( x[b,order[n],:]·Wd[k,0:256] + r(b,n)·Wd[k,256] + bd[k] )
// written TRANSPOSED as z_t[b][k][n] so the FFT kernel reads contiguous rows.
// block = (b, 64 rows). thread t: k = t&31, row-group = t>>5 (8 rows each).
// ---------------------------------------------------------------------------
__global__ void zgemm_kernel(const float* __restrict__ x,
                             const float* __restrict__ coords,
                             const float* __restrict__ Wd,
                             const float* __restrict__ bd,
                             const int*   __restrict__ order,
                             float*       __restrict__ z_t) {
    __shared__ float sWd[BN_][257];
    __shared__ float sbd[BN_];
    __shared__ float ztile[BN_][65];   // +1 pad: avoid 32-way bank conflict on write

    const int blk = blockIdx.x;           // 2048 = 16 * 128
    const int b   = blk >> 7;
    const int n0  = (blk & 127) << 6;     // *64
    const int t   = threadIdx.x;

    for (int i = t; i < BN_ * 257; i += 256) sWd[i / 257][i % 257] = Wd[i];
    if (t < BN_) sbd[t] = bd[t];
    __syncthreads();

    const int k  = t & 31;
    const int rg = t >> 5;                // 0..7

    for (int j = 0; j < 8; ++j) {
        const int nl = rg * 8 + j;
        const int n  = n0 + nl;
        const int od = order[b * N_ + n];
        const float* px = x + ((size_t)b * N_ + od) * D_;
        float s = sbd[k];
        #pragma unroll 4
        for (int d = 0; d < D_; d += 4) {
            float4 xv = *(const float4*)(px + d);
            s += xv.x * sWd[k][d]     + xv.y * sWd[k][d + 1]
               + xv.z * sWd[k][d + 2] + xv.w * sWd[k][d + 3];
        }
        const float* c = coords + ((size_t)b * N_ + n) * 3;
        float rr = sqrtf(c[0] * c[0] + c[1] * c[1] + c[2] * c[2]);
        s += rr * sWd[k][256];
        ztile[k][nl] = fmaxf(s, 0.0f);
    }
    __syncthreads();

    // transposed, coalesced store: z_t[b][k][n0+nn]
    for (int e = t; e < BN_ * 64; e += 256) {
        int kk = e >> 6, nn = e & 63;
        z_t[((size_t)(b * BN_ + kk)) * N_ + n0 + nn] = ztile[kk][nn];
    }
}

// ---------------------------------------------------------------------------
// K3: tiny precompute G = Wu @ V   [256,4]
// ---------------------------------------------------------------------------
__global__ void g_kernel(const float* __restrict__ Wu, const float* __restrict__ V,
                         float* __restrict__ G) {
    const int d = threadIdx.x;   // 256
    for (int r = 0; r < R_; ++r) {
        float s = 0.0f;
        for (int kk = 0; kk < BN_; ++kk) s += Wu[d * BN_ + kk] * V[kk * R_ + r];
        G[d * R_ + r] = s;
    }
}

// ---------------------------------------------------------------------------
// K4: per-(b,k) length-8192 FFT -> multiply H -> IFFT -> real part, in place.
// Forward: radix-2 DIF (natural in -> bit-reversed out).
// H applied at bit-reversed positions. Inverse: radix-2 DIT (bit-rev in ->
// natural out, conjugate twiddles, 1/N scale).
// Dynamic LDS: re[8192] im[8192] twc[4096] tws[4096] = 96 KB.
// ---------------------------------------------------------------------------
__global__ void fft_filter_kernel(float* __restrict__ zy,
                                  const float* __restrict__ logit_d) {
    extern __shared__ float sm[];
    float* re  = sm;
    float* im  = sm + N_;
    float* twc = sm + 2 * N_;
    float* tws = sm + 2 * N_ + N_ / 2;

    const int bk = blockIdx.x;     // 512
    const int b  = bk >> 5;
    const int k  = bk & 31;
    const int t  = threadIdx.x;

    float* row = zy + (size_t)(b * BN_ + k) * N_;

    for (int i = t; i < N_; i += 256) { re[i] = row[i]; im[i] = 0.0f; }

    const float c2pi = 6.28318530717958647692f;
    for (int i = t; i < N_ / 2; i += 256) {
        float ang = -c2pi * (float)i / (float)N_;
        float s, c;
        sincosf(ang, &s, &c);
        twc[i] = c; tws[i] = s;
    }
    float d = logit_d[k];
    d = fminf(fmaxf(d, -10.0f), 10.0f);
    __syncthreads();

    // ---- forward DIF ----
    for (int half = N_ / 2; half >= 1; half >>= 1) {
        const int step = (N_ / 2) / half;
        for (int g = t; g < N_ / 2; g += 256) {
            int jj = g & (half - 1);
            int i0 = ((g - jj) << 1) + jj;
            int i1 = i0 + half;
            float ur = re[i0], ui = im[i0];
            float vr = re[i1], vi = im[i1];
            re[i0] = ur + vr; im[i0] = ui + vi;
            float sr = ur - vr, si = ui - vi;
            int ti = jj * step;
            float c = twc[ti], s = tws[ti];
            re[i1] = sr * c - si * s;
            im[i1] = sr * s + si * c;
        }
        __syncthreads();
    }

    // ---- pointwise H at bit-reversed frequency index ----
    for (int i = t; i < N_; i += 256) {
        int kk = (int)(__brev((unsigned)i) >> (32 - LOGN));
        float w = c2pi * (float)kk / (float)(N_ - 1);
        float H = expf(-w * d);
        re[i] *= H; im[i] *= H;
    }
    __syncthreads();

    // ---- inverse DIT (conjugate twiddles) ----
    for (int half = 1; half <= N_ / 2; half <<= 1) {
        const int step = (N_ / 2) / half;
        for (int g = t; g < N_ / 2; g += 256) {
            int jj = g & (half - 1);
            int i0 = ((g - jj) << 1) + jj;
            int i1 = i0 + half;
            int ti = jj * step;
            float c = twc[ti], s = -tws[ti];
            float vr = re[i1], vi = im[i1];
            float tr = vr * c - vi * s;
            float tii = vr * s + vi * c;
            float ur = re[i0], ui = im[i0];
            re[i0] = ur + tr;  im[i0] = ui + tii;
            re[i1] = ur - tr;  im[i1] = ui - tii;
        }
        __syncthreads();
    }

    const float inv = 1.0f / (float)N_;
    for (int i = t; i < N_; i += 256) row[i] = re[i] * inv;
}

// ---------------------------------------------------------------------------
// K5: t[b,n,r] = sum_k y[b,k,n] * U[k,r];  out = x + t @ G^T + bu
// block = (b, 64 rows of n); phase A builds t_tile[64][4], phase B streams x.
// ---------------------------------------------------------------------------
__global__ void out_kernel(const float* __restrict__ x,
                           const float* __restrict__ y_t,
                           const float* __restrict__ U,
                           const float* __restrict__ G,
                           const float* __restrict__ bu,
                           float*       __restrict__ out) {
    __shared__ float ttile[64][R_];
    const int blk = blockIdx.x;          // 2048
    const int b   = blk >> 7;
    const int n0  = (blk & 127) << 6;
    const int t   = threadIdx.x;

    // phase A: rank-4 projection of y
    {
        const int nl = t >> 2, r = t & 3;
        const float* yb = y_t + (size_t)b * BN_ * N_ + n0 + nl;
        float s = 0.0f;
        #pragma unroll
        for (int kk = 0; kk < BN_; ++kk) s += yb[(size_t)kk * N_] * U[kk * R_ + r];
        ttile[nl][r] = s;
    }
    __syncthreads();

    // phase B: out rows, one d per thread
    float4 g = *(const float4*)(G + t * 4);
    float bv = bu[t];
    const float* xb = x   + ((size_t)b * N_ + n0) * D_;
    float*       ob = out + ((size_t)b * N_ + n0) * D_;
    for (int nl = 0; nl < 64; ++nl) {
        float t0 = ttile[nl][0], t1 = ttile[nl][1];
        float t2 = ttile[nl][2], t3 = ttile[nl][3];
        ob[nl * D_ + t] = xb[nl * D_ + t]
                        + t0 * g.x + t1 * g.y + t2 * g.z + t3 * g.w + bv;
    }
}

// ---------------------------------------------------------------------------
extern "C" void kernel_launch(void* const* d_in, const int* in_sizes, int n_in,
                              void* d_out, int out_size, void* d_ws, size_t ws_size,
                              hipStream_t stream) {
    const float* x       = (const float*)d_in[0];
    const float* coords  = (const float*)d_in[1];
    const float* Wd      = (const float*)d_in[2];
    const float* bd      = (const float*)d_in[3];
    const float* U       = (const float*)d_in[4];
    const float* V       = (const float*)d_in[5];
    const float* logit_d = (const float*)d_in[6];
    const float* Wu      = (const float*)d_in[7];
    const float* bu      = (const float*)d_in[8];
    float* out = (float*)d_out;

    char* ws = (char*)d_ws;
    int*   order = (int*)ws;                           // 16*8192*4   = 512 KB
    float* G     = (float*)(ws + 512 * 1024);          // 256*4*4     = 4 KB
    float* zy    = (float*)(ws + 1024 * 1024);         // 16*32*8192*4 = 16 MB (z, then y in-place)

    sort_kernel<<<dim3(B_), dim3(256), 64 * 1024, stream>>>(coords, order);
    zgemm_kernel<<<dim3(B_ * 128), dim3(256), 0, stream>>>(x, coords, Wd, bd, order, zy);
    g_kernel<<<dim3(1), dim3(256), 0, stream>>>(Wu, V, G);
    fft_filter_kernel<<<dim3(B_ * BN_), dim3(256), 96 * 1024, stream>>>(zy, logit_d);
    out_kernel<<<dim3(B_ * 128), dim3(256), 0, stream>>>(x, zy, U, G, bu, out);
}

// Round 2
// 338.048 us; speedup vs baseline: 1.9915x; 1.9915x over previous
//
#include <hip/hip_runtime.h>
#include <math.h>

#define B_    16
#define N_    8192
#define D_    256
#define BN_   32
#define R_    4
#define LOGN  13

// ---------------------------------------------------------------------------
// Morton helpers (exact replica of reference bit-interleave)
// ---------------------------------------------------------------------------
__device__ __forceinline__ unsigned long long interleave3(unsigned long long v) {
    v = v & 2097151ULL;
    v = v | (v << 32);
    v = v & 8725724278095871ULL;
    v = v | ((v << 16) & 8725728556220671ULL);
    v = v | ((v << 8)  & 282506020581391ULL);
    v = v | ((v << 4)  & 294878547030211ULL);
    v = v | ((v << 2)  & 321685687669321ULL);
    return v;
}

__device__ __forceinline__ long long quant10(float c) {
    long long v = (long long)(c * 1023.0f);   // trunc toward zero, matches astype(int64)
    v = v < 0 ? 0 : (v > 1023 ? 1023 : v);
    return v;
}

// ---------------------------------------------------------------------------
// K1: per-batch stable argsort of morton keys via bitonic sort in LDS.
// key = (morton << 13) | index  -> stable tie-break identical to jnp.argsort.
// 1024 threads, exactly 4 pairs per thread per stage; batched loads then
// unconditional min/max writes (no divergence, deep LDS pipelining).
// ---------------------------------------------------------------------------
__global__ __launch_bounds__(1024)
void sort_kernel(const float* __restrict__ coords, int* __restrict__ order) {
    extern __shared__ unsigned long long skey[];    // 8192 * 8B = 64 KB
    const int b = blockIdx.x;
    const int t = threadIdx.x;

    for (int i = t; i < N_; i += 1024) {
        const float* c = coords + ((size_t)b * N_ + i) * 3;
        unsigned long long mx = interleave3((unsigned long long)quant10(c[0]));
        unsigned long long my = interleave3((unsigned long long)quant10(c[1]));
        unsigned long long mz = interleave3((unsigned long long)quant10(c[2]));
        unsigned long long m = mx | (my << 1) | (mz << 2);
        skey[i] = (m << LOGN) | (unsigned long long)i;
    }
    __syncthreads();

    for (int size = 2; size <= N_; size <<= 1) {
        for (int s = size >> 1; s > 0; s >>= 1) {
            int i_[4];
            unsigned long long a_[4], b_[4];
            #pragma unroll
            for (int u = 0; u < 4; ++u) {
                int p  = t + u * 1024;            // p in [0, 4096)
                int jj = p & (s - 1);
                int i  = ((p - jj) << 1) + jj;    // insert 0-bit at stride position
                i_[u]  = i;
                a_[u]  = skey[i];
                b_[u]  = skey[i + s];
            }
            #pragma unroll
            for (int u = 0; u < 4; ++u) {
                bool up = ((i_[u] & size) == 0);
                unsigned long long lo = a_[u] < b_[u] ? a_[u] : b_[u];
                unsigned long long hi = a_[u] < b_[u] ? b_[u] : a_[u];
                skey[i_[u]]     = up ? lo : hi;
                skey[i_[u] + s] = up ? hi : lo;
            }
            __syncthreads();
        }
    }
    for (int i = t; i < N_; i += 1024)
        order[b * N_ + i] = (int)(skey[i] & (unsigned long long)(N_ - 1));
}

// ---------------------------------------------------------------------------
// K2: z[b,n,k] = relu( x[b,order[n],:]·Wd[k,0:256] + r(b,n)·Wd[k,256] + bd[k] )
// written TRANSPOSED as z_t[b][k][n] so the FFT kernel reads contiguous rows.
// ---------------------------------------------------------------------------
__global__ void zgemm_kernel(const float* __restrict__ x,
                             const float* __restrict__ coords,
                             const float* __restrict__ Wd,
                             const float* __restrict__ bd,
                             const int*   __restrict__ order,
                             float*       __restrict__ z_t) {
    __shared__ float sWd[BN_][257];
    __shared__ float sbd[BN_];
    __shared__ float ztile[BN_][65];   // +1 pad: avoid 32-way bank conflict on write

    const int blk = blockIdx.x;           // 2048 = 16 * 128
    const int b   = blk >> 7;
    const int n0  = (blk & 127) << 6;     // *64
    const int t   = threadIdx.x;

    for (int i = t; i < BN_ * 257; i += 256) sWd[i / 257][i % 257] = Wd[i];
    if (t < BN_) sbd[t] = bd[t];
    __syncthreads();

    const int k  = t & 31;
    const int rg = t >> 5;                // 0..7

    for (int j = 0; j < 8; ++j) {
        const int nl = rg * 8 + j;
        const int n  = n0 + nl;
        const int od = order[b * N_ + n];
        const float* px = x + ((size_t)b * N_ + od) * D_;
        float s = sbd[k];
        #pragma unroll 4
        for (int d = 0; d < D_; d += 4) {
            float4 xv = *(const float4*)(px + d);
            s += xv.x * sWd[k][d]     + xv.y * sWd[k][d + 1]
               + xv.z * sWd[k][d + 2] + xv.w * sWd[k][d + 3];
        }
        const float* c = coords + ((size_t)b * N_ + n) * 3;
        float rr = sqrtf(c[0] * c[0] + c[1] * c[1] + c[2] * c[2]);
        s += rr * sWd[k][256];
        ztile[k][nl] = fmaxf(s, 0.0f);
    }
    __syncthreads();

    // transposed, coalesced store: z_t[b][k][n0+nn]
    for (int e = t; e < BN_ * 64; e += 256) {
        int kk = e >> 6, nn = e & 63;
        z_t[((size_t)(b * BN_ + kk)) * N_ + n0 + nn] = ztile[kk][nn];
    }
}

// ---------------------------------------------------------------------------
// K3: tiny precompute G = Wu @ V   [256,4]
// ---------------------------------------------------------------------------
__global__ void g_kernel(const float* __restrict__ Wu, const float* __restrict__ V,
                         float* __restrict__ G) {
    const int d = threadIdx.x;   // 256
    for (int r = 0; r < R_; ++r) {
        float s = 0.0f;
        for (int kk = 0; kk < BN_; ++kk) s += Wu[d * BN_ + kk] * V[kk * R_ + r];
        G[d * R_ + r] = s;
    }
}

// ---------------------------------------------------------------------------
// K4: per-(b,k) length-8192 FFT -> multiply H -> IFFT -> real part, in place.
// Forward: radix-2 DIF (natural in -> bit-reversed out), H applied at
// bit-reversed positions, inverse DIT (bit-rev in -> natural out).
// (re,im) packed as float2 (ds b64). Twiddles via __sincosf on the fly:
// LDS = 64 KB -> 2 blocks/CU, all 512 blocks resident.
// ---------------------------------------------------------------------------
__global__ __launch_bounds__(512)
void fft_filter_kernel(float* __restrict__ zy,
                       const float* __restrict__ logit_d) {
    extern __shared__ float2 cbuf[];   // 8192 * 8B = 64 KB

    const int bk = blockIdx.x;     // 512
    const int b  = bk >> 5;
    const int k  = bk & 31;
    const int t  = threadIdx.x;

    float* row = zy + (size_t)(b * BN_ + k) * N_;

    for (int i = t; i < N_; i += 512) cbuf[i] = make_float2(row[i], 0.0f);

    float d = logit_d[k];
    d = fminf(fmaxf(d, -10.0f), 10.0f);
    __syncthreads();

    const float cpi  = 3.14159265358979323846f;
    const float c2pi = 6.28318530717958647692f;

    // ---- forward DIF ----  twiddle angle = -pi * jj / half
    for (int half = N_ / 2; half >= 1; half >>= 1) {
        const float astep = -cpi / (float)half;
        #pragma unroll
        for (int u = 0; u < 8; ++u) {
            int g  = t + u * 512;              // 4096 butterflies
            int jj = g & (half - 1);
            int i0 = ((g - jj) << 1) + jj;
            int i1 = i0 + half;
            float2 uv = cbuf[i0], vv = cbuf[i1];
            cbuf[i0] = make_float2(uv.x + vv.x, uv.y + vv.y);
            float sr = uv.x - vv.x, si = uv.y - vv.y;
            float ss, cc;
            __sincosf(astep * (float)jj, &ss, &cc);
            cbuf[i1] = make_float2(sr * cc - si * ss, sr * ss + si * cc);
        }
        __syncthreads();
    }

    // ---- pointwise H at bit-reversed frequency index ----
    #pragma unroll
    for (int u = 0; u < 16; ++u) {
        int i  = t + u * 512;
        int kk = (int)(__brev((unsigned)i) >> (32 - LOGN));
        float w = c2pi * (float)kk / (float)(N_ - 1);
        float H = expf(-w * d);
        float2 v = cbuf[i];
        cbuf[i] = make_float2(v.x * H, v.y * H);
    }
    __syncthreads();

    // ---- inverse DIT (conjugate twiddles: angle = +pi * jj / half) ----
    for (int half = 1; half <= N_ / 2; half <<= 1) {
        const float astep = cpi / (float)half;
        #pragma unroll
        for (int u = 0; u < 8; ++u) {
            int g  = t + u * 512;
            int jj = g & (half - 1);
            int i0 = ((g - jj) << 1) + jj;
            int i1 = i0 + half;
            float ss, cc;
            __sincosf(astep * (float)jj, &ss, &cc);
            float2 vv = cbuf[i1];
            float tr  = vv.x * cc - vv.y * ss;
            float tii = vv.x * ss + vv.y * cc;
            float2 uv = cbuf[i0];
            cbuf[i0] = make_float2(uv.x + tr,  uv.y + tii);
            cbuf[i1] = make_float2(uv.x - tr,  uv.y - tii);
        }
        __syncthreads();
    }

    const float inv = 1.0f / (float)N_;
    for (int i = t; i < N_; i += 512) row[i] = cbuf[i].x * inv;
}

// ---------------------------------------------------------------------------
// K5: t[b,n,r] = sum_k y[b,k,n] * U[k,r];  out = x + t @ G^T + bu
// ---------------------------------------------------------------------------
__global__ void out_kernel(const float* __restrict__ x,
                           const float* __restrict__ y_t,
                           const float* __restrict__ U,
                           const float* __restrict__ G,
                           const float* __restrict__ bu,
                           float*       __restrict__ out) {
    __shared__ float ttile[64][R_];
    const int blk = blockIdx.x;          // 2048
    const int b   = blk >> 7;
    const int n0  = (blk & 127) << 6;
    const int t   = threadIdx.x;

    // phase A: rank-4 projection of y
    {
        const int nl = t >> 2, r = t & 3;
        const float* yb = y_t + (size_t)b * BN_ * N_ + n0 + nl;
        float s = 0.0f;
        #pragma unroll
        for (int kk = 0; kk < BN_; ++kk) s += yb[(size_t)kk * N_] * U[kk * R_ + r];
        ttile[nl][r] = s;
    }
    __syncthreads();

    // phase B: out rows, one d per thread
    float4 g = *(const float4*)(G + t * 4);
    float bv = bu[t];
    const float* xb = x   + ((size_t)b * N_ + n0) * D_;
    float*       ob = out + ((size_t)b * N_ + n0) * D_;
    for (int nl = 0; nl < 64; ++nl) {
        float t0 = ttile[nl][0], t1 = ttile[nl][1];
        float t2 = ttile[nl][2], t3 = ttile[nl][3];
        ob[nl * D_ + t] = xb[nl * D_ + t]
                        + t0 * g.x + t1 * g.y + t2 * g.z + t3 * g.w + bv;
    }
}

// ---------------------------------------------------------------------------
extern "C" void kernel_launch(void* const* d_in, const int* in_sizes, int n_in,
                              void* d_out, int out_size, void* d_ws, size_t ws_size,
                              hipStream_t stream) {
    const float* x       = (const float*)d_in[0];
    const float* coords  = (const float*)d_in[1];
    const float* Wd      = (const float*)d_in[2];
    const float* bd      = (const float*)d_in[3];
    const float* U       = (const float*)d_in[4];
    const float* V       = (const float*)d_in[5];
    const float* logit_d = (const float*)d_in[6];
    const float* Wu      = (const float*)d_in[7];
    const float* bu      = (const float*)d_in[8];
    float* out = (float*)d_out;

    char* ws = (char*)d_ws;
    int*   order = (int*)ws;                           // 16*8192*4   = 512 KB
    float* G     = (float*)(ws + 512 * 1024);          // 256*4*4     = 4 KB
    float* zy    = (float*)(ws + 1024 * 1024);         // 16*32*8192*4 = 16 MB (z, then y in-place)

    sort_kernel<<<dim3(B_), dim3(1024), 64 * 1024, stream>>>(coords, order);
    zgemm_kernel<<<dim3(B_ * 128), dim3(256), 0, stream>>>(x, coords, Wd, bd, order, zy);
    g_kernel<<<dim3(1), dim3(256), 0, stream>>>(Wu, V, G);
    fft_filter_kernel<<<dim3(B_ * BN_), dim3(512), 64 * 1024, stream>>>(zy, logit_d);
    out_kernel<<<dim3(B_ * 128), dim3(256), 0, stream>>>(x, zy, U, G, bu, out);
}

// Round 3
// 219.126 us; speedup vs baseline: 3.0723x; 1.5427x over previous
//
#include <hip/hip_runtime.h>
#include <math.h>

#define B_    16
#define N_    8192
#define D_    256
#define BN_   32
#define R_    4
#define LOGN  13

typedef float  f32x4  __attribute__((ext_vector_type(4)));
typedef short  s16x8  __attribute__((ext_vector_type(8)));

// ---------------------------------------------------------------------------
// Morton helpers (exact replica of reference bit-interleave)
// ---------------------------------------------------------------------------
__device__ __forceinline__ unsigned long long interleave3(unsigned long long v) {
    v = v & 2097151ULL;
    v = v | (v << 32);
    v = v & 8725724278095871ULL;
    v = v | ((v << 16) & 8725728556220671ULL);
    v = v | ((v << 8)  & 282506020581391ULL);
    v = v | ((v << 4)  & 294878547030211ULL);
    v = v | ((v << 2)  & 321685687669321ULL);
    return v;
}

__device__ __forceinline__ long long quant10(float c) {
    long long v = (long long)(c * 1023.0f);
    v = v < 0 ? 0 : (v > 1023 ? 1023 : v);
    return v;
}

__device__ __forceinline__ unsigned short f2bf(float f) {
    unsigned u = __float_as_uint(f);
    u = (u + 0x7FFF + ((u >> 16) & 1)) >> 16;   // RNE
    return (unsigned short)u;
}

// ---------------------------------------------------------------------------
// S1: 32 blocks (b, half). Bitonic phases size=2..4096 on 4096 keys in LDS.
// Direction from GLOBAL index -> output halves form one bitonic sequence.
// ---------------------------------------------------------------------------
__global__ __launch_bounds__(1024)
void sort1_kernel(const float* __restrict__ coords, unsigned long long* __restrict__ keys) {
    __shared__ unsigned long long skey[4096];    // 32 KB
    const int b = blockIdx.x >> 1;
    const int h = blockIdx.x & 1;
    const int t = threadIdx.x;
    const int gbase = h * 4096;

    for (int i = t; i < 4096; i += 1024) {
        const int gi = gbase + i;
        const float* c = coords + ((size_t)b * N_ + gi) * 3;
        unsigned long long mx = interleave3((unsigned long long)quant10(c[0]));
        unsigned long long my = interleave3((unsigned long long)quant10(c[1]));
        unsigned long long mz = interleave3((unsigned long long)quant10(c[2]));
        unsigned long long m = mx | (my << 1) | (mz << 2);
        skey[i] = (m << LOGN) | (unsigned long long)gi;
    }
    __syncthreads();

    for (int size = 2; size <= 4096; size <<= 1) {
        for (int s = size >> 1; s > 0; s >>= 1) {
            int i_[2];
            unsigned long long a_[2], b_[2];
            #pragma unroll
            for (int u = 0; u < 2; ++u) {
                int p  = t + u * 1024;            // 2048 pairs
                int jj = p & (s - 1);
                int i  = ((p - jj) << 1) + jj;
                i_[u] = i; a_[u] = skey[i]; b_[u] = skey[i + s];
            }
            #pragma unroll
            for (int u = 0; u < 2; ++u) {
                bool up = (((gbase + i_[u]) & size) == 0);
                unsigned long long lo = a_[u] < b_[u] ? a_[u] : b_[u];
                unsigned long long hi = a_[u] < b_[u] ? b_[u] : a_[u];
                skey[i_[u]]     = up ? lo : hi;
                skey[i_[u] + s] = up ? hi : lo;
            }
            __syncthreads();
        }
    }
    for (int i = t; i < 4096; i += 1024)
        keys[(size_t)b * N_ + gbase + i] = skey[i];
}

// ---------------------------------------------------------------------------
// S2: 16 blocks. Final merge phase (size=8192, ascending), emit inverse perm.
// inv[b][orig_row] = sorted position.
// ---------------------------------------------------------------------------
__global__ __launch_bounds__(1024)
void sort2_kernel(const unsigned long long* __restrict__ keys, int* __restrict__ inv) {
    __shared__ unsigned long long skey[N_];      // 64 KB
    const int b = blockIdx.x;
    const int t = threadIdx.x;

    for (int i = t; i < N_; i += 1024) skey[i] = keys[(size_t)b * N_ + i];
    __syncthreads();

    for (int s = 4096; s > 0; s >>= 1) {
        int i_[4];
        unsigned long long a_[4], b_[4];
        #pragma unroll
        for (int u = 0; u < 4; ++u) {
            int p  = t + u * 1024;                // 4096 pairs
            int jj = p & (s - 1);
            int i  = ((p - jj) << 1) + jj;
            i_[u] = i; a_[u] = skey[i]; b_[u] = skey[i + s];
        }
        #pragma unroll
        for (int u = 0; u < 4; ++u) {
            unsigned long long lo = a_[u] < b_[u] ? a_[u] : b_[u];
            unsigned long long hi = a_[u] < b_[u] ? b_[u] : a_[u];
            skey[i_[u]]     = lo;
            skey[i_[u] + s] = hi;
        }
        __syncthreads();
    }
    for (int i = t; i < N_; i += 1024)
        inv[b * N_ + (int)(skey[i] & (unsigned long long)(N_ - 1))] = i;
}

// ---------------------------------------------------------------------------
// K2 (MFMA): natural-order x, z scattered via inv.
// Block: 256 thr / 4 waves, 64 natural rows. LDS: x-tile bf16 [64][256] and
// Wd bf16 [32][256], both XOR-swizzled (^ (row&7)<<4) for conflict-free
// ds_read_b128 MFMA fragments. D = Wd_frag(16ch x 32K) * x_frag(32K x 16row).
// Epilogue: + rr(coords[p])*Wd[:,256] + bd, relu, scatter to z_t[b][k][p].
// ---------------------------------------------------------------------------
__global__ __launch_bounds__(256)
void zgemm_kernel(const float* __restrict__ x,
                  const float* __restrict__ coords,
                  const float* __restrict__ Wd,
                  const float* __restrict__ bd,
                  const int*   __restrict__ inv,
                  float*       __restrict__ z_t) {
    __shared__ char xlds[64 * 256 * 2];    // 32 KB
    __shared__ char wdlds[32 * 256 * 2];   // 16 KB
    __shared__ float sWdLast[BN_];
    __shared__ float sbd[BN_];

    const int blk = blockIdx.x;           // 2048 = 16 * 128
    const int b   = blk >> 7;
    const int m0  = (blk & 127) << 6;     // within-batch natural row base
    const int t   = threadIdx.x;
    const int w   = t >> 6;
    const int l   = t & 63;

    // ---- stage x tile: wave reads one full row (1KB) per instruction ----
    for (int rr_ = 0; rr_ < 16; ++rr_) {
        const int row = rr_ * 4 + w;
        const float4 v = *(const float4*)(x + ((size_t)(b * N_ + m0 + row)) * D_ + l * 4);
        unsigned off = (row << 9) + (l << 3);
        off ^= (row & 7) << 4;
        ushort4 pk = make_ushort4(f2bf(v.x), f2bf(v.y), f2bf(v.z), f2bf(v.w));
        *(ushort4*)(xlds + off) = pk;
    }
    // ---- stage Wd (32 rows of 257) ----
    for (int rr_ = 0; rr_ < 8; ++rr_) {
        const int row = rr_ * 4 + w;
        const float4 v = *(const float4*)(Wd + (size_t)row * 257 + l * 4);
        unsigned off = (row << 9) + (l << 3);
        off ^= (row & 7) << 4;
        ushort4 pk = make_ushort4(f2bf(v.x), f2bf(v.y), f2bf(v.z), f2bf(v.w));
        *(ushort4*)(wdlds + off) = pk;
    }
    if (t < BN_) { sWdLast[t] = Wd[(size_t)t * 257 + 256]; sbd[t] = bd[t]; }
    __syncthreads();

    // ---- MFMA: wave w owns x-rows [w*16, w*16+16) x all 32 channels ----
    const int lg = l >> 4;     // 0..3
    const int lm = l & 15;
    f32x4 acc0 = {0.f, 0.f, 0.f, 0.f};
    f32x4 acc1 = {0.f, 0.f, 0.f, 0.f};
    const int xr = w * 16 + lm;
    #pragma unroll
    for (int kc = 0; kc < 8; ++kc) {
        const unsigned doff = kc * 64 + lg * 16;
        s16x8 bfr = *(const s16x8*)(xlds  + ((((unsigned)xr << 9) + doff) ^ ((xr & 7) << 4)));
        s16x8 a0  = *(const s16x8*)(wdlds + ((((unsigned)lm << 9) + doff) ^ ((lm & 7) << 4)));
        s16x8 a1  = *(const s16x8*)(wdlds + ((((unsigned)(16 + lm) << 9) + doff) ^ ((lm & 7) << 4)));
        acc0 = __builtin_amdgcn_mfma_f32_16x16x32_bf16(a0, bfr, acc0, 0, 0, 0);
        acc1 = __builtin_amdgcn_mfma_f32_16x16x32_bf16(a1, bfr, acc1, 0, 0, 0);
    }

    // ---- epilogue: radius + bias, relu, scatter ----
    const int m = m0 + w * 16 + lm;                  // natural row (D-col)
    const int p = inv[b * N_ + m];                   // sorted position
    const float* c = coords + ((size_t)(b * N_ + p)) * 3;
    const float rr = sqrtf(c[0] * c[0] + c[1] * c[1] + c[2] * c[2]);
    float* zb = z_t + (size_t)b * BN_ * N_ + p;
    #pragma unroll
    for (int j = 0; j < 4; ++j) {
        const int kk = lg * 4 + j;
        float v0 = acc0[j] + rr * sWdLast[kk]      + sbd[kk];
        float v1 = acc1[j] + rr * sWdLast[kk + 16] + sbd[kk + 16];
        zb[(size_t)kk * N_]        = fmaxf(v0, 0.0f);
        zb[(size_t)(kk + 16) * N_] = fmaxf(v1, 0.0f);
    }
}

// ---------------------------------------------------------------------------
// K3: tiny precompute G = Wu @ V   [256,4]
// ---------------------------------------------------------------------------
__global__ void g_kernel(const float* __restrict__ Wu, const float* __restrict__ V,
                         float* __restrict__ G) {
    const int d = threadIdx.x;   // 256
    for (int r = 0; r < R_; ++r) {
        float s = 0.0f;
        for (int kk = 0; kk < BN_; ++kk) s += Wu[d * BN_ + kk] * V[kk * R_ + r];
        G[d * R_ + r] = s;
    }
}

// ---------------------------------------------------------------------------
// K4: per-(b,k) length-8192 FFT -> H -> IFFT -> real, in place. float2 LDS.
// ---------------------------------------------------------------------------
__global__ __launch_bounds__(512)
void fft_filter_kernel(float* __restrict__ zy,
                       const float* __restrict__ logit_d) {
    extern __shared__ float2 cbuf[];   // 64 KB

    const int bk = blockIdx.x;     // 512
    const int b  = bk >> 5;
    const int k  = bk & 31;
    const int t  = threadIdx.x;

    float* row = zy + (size_t)(b * BN_ + k) * N_;

    for (int i = t; i < N_; i += 512) cbuf[i] = make_float2(row[i], 0.0f);

    float d = logit_d[k];
    d = fminf(fmaxf(d, -10.0f), 10.0f);
    __syncthreads();

    const float cpi  = 3.14159265358979323846f;
    const float c2pi = 6.28318530717958647692f;

    for (int half = N_ / 2; half >= 1; half >>= 1) {
        const float astep = -cpi / (float)half;
        #pragma unroll
        for (int u = 0; u < 8; ++u) {
            int g  = t + u * 512;
            int jj = g & (half - 1);
            int i0 = ((g - jj) << 1) + jj;
            int i1 = i0 + half;
            float2 uv = cbuf[i0], vv = cbuf[i1];
            cbuf[i0] = make_float2(uv.x + vv.x, uv.y + vv.y);
            float sr = uv.x - vv.x, si = uv.y - vv.y;
            float ss, cc;
            __sincosf(astep * (float)jj, &ss, &cc);
            cbuf[i1] = make_float2(sr * cc - si * ss, sr * ss + si * cc);
        }
        __syncthreads();
    }

    #pragma unroll
    for (int u = 0; u < 16; ++u) {
        int i  = t + u * 512;
        int kk = (int)(__brev((unsigned)i) >> (32 - LOGN));
        float w = c2pi * (float)kk / (float)(N_ - 1);
        float H = expf(-w * d);
        float2 v = cbuf[i];
        cbuf[i] = make_float2(v.x * H, v.y * H);
    }
    __syncthreads();

    for (int half = 1; half <= N_ / 2; half <<= 1) {
        const float astep = cpi / (float)half;
        #pragma unroll
        for (int u = 0; u < 8; ++u) {
            int g  = t + u * 512;
            int jj = g & (half - 1);
            int i0 = ((g - jj) << 1) + jj;
            int i1 = i0 + half;
            float ss, cc;
            __sincosf(astep * (float)jj, &ss, &cc);
            float2 vv = cbuf[i1];
            float tr  = vv.x * cc - vv.y * ss;
            float tii = vv.x * ss + vv.y * cc;
            float2 uv = cbuf[i0];
            cbuf[i0] = make_float2(uv.x + tr,  uv.y + tii);
            cbuf[i1] = make_float2(uv.x - tr,  uv.y - tii);
        }
        __syncthreads();
    }

    const float inv = 1.0f / (float)N_;
    for (int i = t; i < N_; i += 512) row[i] = cbuf[i].x * inv;
}

// ---------------------------------------------------------------------------
// K5: t[b,n,r] = sum_k y[b,k,n] * U[k,r];  out = x + t @ G^T + bu
// ---------------------------------------------------------------------------
__global__ void out_kernel(const float* __restrict__ x,
                           const float* __restrict__ y_t,
                           const float* __restrict__ U,
                           const float* __restrict__ G,
                           const float* __restrict__ bu,
                           float*       __restrict__ out) {
    __shared__ float ttile[64][R_];
    const int blk = blockIdx.x;          // 2048
    const int b   = blk >> 7;
    const int n0  = (blk & 127) << 6;
    const int t   = threadIdx.x;

    {
        const int nl = t >> 2, r = t & 3;
        const float* yb = y_t + (size_t)b * BN_ * N_ + n0 + nl;
        float s = 0.0f;
        #pragma unroll
        for (int kk = 0; kk < BN_; ++kk) s += yb[(size_t)kk * N_] * U[kk * R_ + r];
        ttile[nl][r] = s;
    }
    __syncthreads();

    float4 g = *(const float4*)(G + t * 4);
    float bv = bu[t];
    const float* xb = x   + ((size_t)b * N_ + n0) * D_;
    float*       ob = out + ((size_t)b * N_ + n0) * D_;
    for (int nl = 0; nl < 64; ++nl) {
        float t0 = ttile[nl][0], t1 = ttile[nl][1];
        float t2 = ttile[nl][2], t3 = ttile[nl][3];
        ob[nl * D_ + t] = xb[nl * D_ + t]
                        + t0 * g.x + t1 * g.y + t2 * g.z + t3 * g.w + bv;
    }
}

// ---------------------------------------------------------------------------
extern "C" void kernel_launch(void* const* d_in, const int* in_sizes, int n_in,
                              void* d_out, int out_size, void* d_ws, size_t ws_size,
                              hipStream_t stream) {
    const float* x       = (const float*)d_in[0];
    const float* coords  = (const float*)d_in[1];
    const float* Wd      = (const float*)d_in[2];
    const float* bd      = (const float*)d_in[3];
    const float* U       = (const float*)d_in[4];
    const float* V       = (const float*)d_in[5];
    const float* logit_d = (const float*)d_in[6];
    const float* Wu      = (const float*)d_in[7];
    const float* bu      = (const float*)d_in[8];
    float* out = (float*)d_out;

    char* ws = (char*)d_ws;
    int*                inv  = (int*)ws;                            // 512 KB
    unsigned long long* keys = (unsigned long long*)(ws + 512*1024); // 1 MB
    float*              G    = (float*)(ws + 1536 * 1024);          // 4 KB
    float*              zy   = (float*)(ws + 2048 * 1024);          // 16 MB

    sort1_kernel<<<dim3(2 * B_), dim3(1024), 0, stream>>>(coords, keys);
    sort2_kernel<<<dim3(B_), dim3(1024), 0, stream>>>(keys, inv);
    zgemm_kernel<<<dim3(B_ * 128), dim3(256), 0, stream>>>(x, coords, Wd, bd, inv, zy);
    g_kernel<<<dim3(1), dim3(256), 0, stream>>>(Wu, V, G);
    fft_filter_kernel<<<dim3(B_ * BN_), dim3(512), 64 * 1024, stream>>>(zy, logit_d);
    out_kernel<<<dim3(B_ * 128), dim3(256), 0, stream>>>(x, zy, U, G, bu, out);
}

// Round 4
// 187.788 us; speedup vs baseline: 3.5850x; 1.1669x over previous
//
#include <hip/hip_runtime.h>
#include <math.h>

#define B_    16
#define N_    8192
#define D_    256
#define BN_   32
#define R_    4
#define LOGN  13

typedef float  f32x4  __attribute__((ext_vector_type(4)));
typedef short  s16x8  __attribute__((ext_vector_type(8)));

// ---------------------------------------------------------------------------
// Morton helpers (exact replica of reference bit-interleave)
// ---------------------------------------------------------------------------
__device__ __forceinline__ unsigned long long interleave3(unsigned long long v) {
    v = v & 2097151ULL;
    v = v | (v << 32);
    v = v & 8725724278095871ULL;
    v = v | ((v << 16) & 8725728556220671ULL);
    v = v | ((v << 8)  & 282506020581391ULL);
    v = v | ((v << 4)  & 294878547030211ULL);
    v = v | ((v << 2)  & 321685687669321ULL);
    return v;
}

__device__ __forceinline__ long long quant10(float c) {
    long long v = (long long)(c * 1023.0f);
    v = v < 0 ? 0 : (v > 1023 ? 1023 : v);
    return v;
}

__device__ __forceinline__ unsigned short f2bf(float f) {
    unsigned u = __float_as_uint(f);
    u = (u + 0x7FFF + ((u >> 16) & 1)) >> 16;   // RNE
    return (unsigned short)u;
}

// ---------------------------------------------------------------------------
// S1: 32 blocks (b, half). Bitonic phases size=2..4096 on 4096 keys in LDS.
// Direction from GLOBAL index -> output halves form one bitonic sequence.
// ---------------------------------------------------------------------------
__global__ __launch_bounds__(1024)
void sort1_kernel(const float* __restrict__ coords, unsigned long long* __restrict__ keys) {
    __shared__ unsigned long long skey[4096];    // 32 KB
    const int b = blockIdx.x >> 1;
    const int h = blockIdx.x & 1;
    const int t = threadIdx.x;
    const int gbase = h * 4096;

    for (int i = t; i < 4096; i += 1024) {
        const int gi = gbase + i;
        const float* c = coords + ((size_t)b * N_ + gi) * 3;
        unsigned long long mx = interleave3((unsigned long long)quant10(c[0]));
        unsigned long long my = interleave3((unsigned long long)quant10(c[1]));
        unsigned long long mz = interleave3((unsigned long long)quant10(c[2]));
        unsigned long long m = mx | (my << 1) | (mz << 2);
        skey[i] = (m << LOGN) | (unsigned long long)gi;
    }
    __syncthreads();

    for (int size = 2; size <= 4096; size <<= 1) {
        for (int s = size >> 1; s > 0; s >>= 1) {
            int i_[2];
            unsigned long long a_[2], b_[2];
            #pragma unroll
            for (int u = 0; u < 2; ++u) {
                int p  = t + u * 1024;            // 2048 pairs
                int jj = p & (s - 1);
                int i  = ((p - jj) << 1) + jj;
                i_[u] = i; a_[u] = skey[i]; b_[u] = skey[i + s];
            }
            #pragma unroll
            for (int u = 0; u < 2; ++u) {
                bool up = (((gbase + i_[u]) & size) == 0);
                unsigned long long lo = a_[u] < b_[u] ? a_[u] : b_[u];
                unsigned long long hi = a_[u] < b_[u] ? b_[u] : a_[u];
                skey[i_[u]]     = up ? lo : hi;
                skey[i_[u] + s] = up ? hi : lo;
            }
            __syncthreads();
        }
    }
    for (int i = t; i < 4096; i += 1024)
        keys[(size_t)b * N_ + gbase + i] = skey[i];
}

// ---------------------------------------------------------------------------
// S2: 16 blocks. Final merge phase (size=8192, ascending).
// Emits order[b][p] = natural index of the p-th smallest key.
// ---------------------------------------------------------------------------
__global__ __launch_bounds__(1024)
void sort2_kernel(const unsigned long long* __restrict__ keys, int* __restrict__ order) {
    __shared__ unsigned long long skey[N_];      // 64 KB
    const int b = blockIdx.x;
    const int t = threadIdx.x;

    for (int i = t; i < N_; i += 1024) skey[i] = keys[(size_t)b * N_ + i];
    __syncthreads();

    for (int s = 4096; s > 0; s >>= 1) {
        int i_[4];
        unsigned long long a_[4], b_[4];
        #pragma unroll
        for (int u = 0; u < 4; ++u) {
            int p  = t + u * 1024;                // 4096 pairs
            int jj = p & (s - 1);
            int i  = ((p - jj) << 1) + jj;
            i_[u] = i; a_[u] = skey[i]; b_[u] = skey[i + s];
        }
        #pragma unroll
        for (int u = 0; u < 4; ++u) {
            unsigned long long lo = a_[u] < b_[u] ? a_[u] : b_[u];
            unsigned long long hi = a_[u] < b_[u] ? b_[u] : a_[u];
            skey[i_[u]]     = lo;
            skey[i_[u] + s] = hi;
        }
        __syncthreads();
    }
    for (int i = t; i < N_; i += 1024)
        order[b * N_ + i] = (int)(skey[i] & (unsigned long long)(N_ - 1));
}

// ---------------------------------------------------------------------------
// K2 (MFMA): processes 64 consecutive SORTED slots p; gathers x rows via
// order[p] (each row load = coalesced 1KB), radius from coords[b][p]
// (sequential), z written at consecutive p (coalesced, no RMW).
// LDS: x-tile bf16 [64][256] and Wd bf16 [32][256], XOR-swizzled for
// conflict-free ds_read_b128 MFMA fragments.
// ---------------------------------------------------------------------------
__global__ __launch_bounds__(256)
void zgemm_kernel(const float* __restrict__ x,
                  const float* __restrict__ coords,
                  const float* __restrict__ Wd,
                  const float* __restrict__ bd,
                  const int*   __restrict__ order,
                  float*       __restrict__ z_t) {
    __shared__ char xlds[64 * 256 * 2];    // 32 KB
    __shared__ char wdlds[32 * 256 * 2];   // 16 KB
    __shared__ float sWdLast[BN_];
    __shared__ float sbd[BN_];

    const int blk = blockIdx.x;           // 2048 = 16 * 128
    const int b   = blk >> 7;
    const int p0  = (blk & 127) << 6;     // sorted-slot base
    const int t   = threadIdx.x;
    const int w   = t >> 6;
    const int l   = t & 63;

    // ---- stage x tile: row = sorted slot, gathered via order ----
    for (int rr_ = 0; rr_ < 16; ++rr_) {
        const int row = rr_ * 4 + w;
        const int od  = order[b * N_ + p0 + row];     // wave-uniform broadcast
        const float4 v = *(const float4*)(x + ((size_t)(b * N_ + od)) * D_ + l * 4);
        unsigned off = (row << 9) + (l << 3);
        off ^= (row & 7) << 4;
        ushort4 pk = make_ushort4(f2bf(v.x), f2bf(v.y), f2bf(v.z), f2bf(v.w));
        *(ushort4*)(xlds + off) = pk;
    }
    // ---- stage Wd (32 rows of 257) ----
    for (int rr_ = 0; rr_ < 8; ++rr_) {
        const int row = rr_ * 4 + w;
        const float4 v = *(const float4*)(Wd + (size_t)row * 257 + l * 4);
        unsigned off = (row << 9) + (l << 3);
        off ^= (row & 7) << 4;
        ushort4 pk = make_ushort4(f2bf(v.x), f2bf(v.y), f2bf(v.z), f2bf(v.w));
        *(ushort4*)(wdlds + off) = pk;
    }
    if (t < BN_) { sWdLast[t] = Wd[(size_t)t * 257 + 256]; sbd[t] = bd[t]; }
    __syncthreads();

    // ---- MFMA: wave w owns sorted slots [w*16, w*16+16) x all 32 channels ----
    const int lg = l >> 4;     // 0..3
    const int lm = l & 15;
    f32x4 acc0 = {0.f, 0.f, 0.f, 0.f};
    f32x4 acc1 = {0.f, 0.f, 0.f, 0.f};
    const int xr = w * 16 + lm;
    #pragma unroll
    for (int kc = 0; kc < 8; ++kc) {
        const unsigned doff = kc * 64 + lg * 16;
        s16x8 bfr = *(const s16x8*)(xlds  + ((((unsigned)xr << 9) + doff) ^ ((xr & 7) << 4)));
        s16x8 a0  = *(const s16x8*)(wdlds + ((((unsigned)lm << 9) + doff) ^ ((lm & 7) << 4)));
        s16x8 a1  = *(const s16x8*)(wdlds + ((((unsigned)(16 + lm) << 9) + doff) ^ ((lm & 7) << 4)));
        acc0 = __builtin_amdgcn_mfma_f32_16x16x32_bf16(a0, bfr, acc0, 0, 0, 0);
        acc1 = __builtin_amdgcn_mfma_f32_16x16x32_bf16(a1, bfr, acc1, 0, 0, 0);
    }

    // ---- epilogue: radius + bias, relu, coalesced store at sorted slot ----
    const int p = p0 + w * 16 + lm;                  // sorted slot
    const float* c = coords + ((size_t)(b * N_ + p)) * 3;
    const float rr = sqrtf(c[0] * c[0] + c[1] * c[1] + c[2] * c[2]);
    float* zb = z_t + (size_t)b * BN_ * N_ + p;
    #pragma unroll
    for (int j = 0; j < 4; ++j) {
        const int kk = lg * 4 + j;
        float v0 = acc0[j] + rr * sWdLast[kk]      + sbd[kk];
        float v1 = acc1[j] + rr * sWdLast[kk + 16] + sbd[kk + 16];
        zb[(size_t)kk * N_]        = fmaxf(v0, 0.0f);
        zb[(size_t)(kk + 16) * N_] = fmaxf(v1, 0.0f);
    }
}

// ---------------------------------------------------------------------------
// K3: tiny precompute G = Wu @ V   [256,4]
// ---------------------------------------------------------------------------
__global__ void g_kernel(const float* __restrict__ Wu, const float* __restrict__ V,
                         float* __restrict__ G) {
    const int d = threadIdx.x;   // 256
    for (int r = 0; r < R_; ++r) {
        float s = 0.0f;
        for (int kk = 0; kk < BN_; ++kk) s += Wu[d * BN_ + kk] * V[kk * R_ + r];
        G[d * R_ + r] = s;
    }
}

// ---------------------------------------------------------------------------
// K4: per-(b,k) length-8192 FFT -> H -> IFFT -> real, in place. float2 LDS.
// ---------------------------------------------------------------------------
__global__ __launch_bounds__(512)
void fft_filter_kernel(float* __restrict__ zy,
                       const float* __restrict__ logit_d) {
    extern __shared__ float2 cbuf[];   // 64 KB

    const int bk = blockIdx.x;     // 512
    const int b  = bk >> 5;
    const int k  = bk & 31;
    const int t  = threadIdx.x;

    float* row = zy + (size_t)(b * BN_ + k) * N_;

    for (int i = t; i < N_; i += 512) cbuf[i] = make_float2(row[i], 0.0f);

    float d = logit_d[k];
    d = fminf(fmaxf(d, -10.0f), 10.0f);
    __syncthreads();

    const float cpi  = 3.14159265358979323846f;
    const float c2pi = 6.28318530717958647692f;

    for (int half = N_ / 2; half >= 1; half >>= 1) {
        const float astep = -cpi / (float)half;
        #pragma unroll
        for (int u = 0; u < 8; ++u) {
            int g  = t + u * 512;
            int jj = g & (half - 1);
            int i0 = ((g - jj) << 1) + jj;
            int i1 = i0 + half;
            float2 uv = cbuf[i0], vv = cbuf[i1];
            cbuf[i0] = make_float2(uv.x + vv.x, uv.y + vv.y);
            float sr = uv.x - vv.x, si = uv.y - vv.y;
            float ss, cc;
            __sincosf(astep * (float)jj, &ss, &cc);
            cbuf[i1] = make_float2(sr * cc - si * ss, sr * ss + si * cc);
        }
        __syncthreads();
    }

    #pragma unroll
    for (int u = 0; u < 16; ++u) {
        int i  = t + u * 512;
        int kk = (int)(__brev((unsigned)i) >> (32 - LOGN));
        float w = c2pi * (float)kk / (float)(N_ - 1);
        float H = expf(-w * d);
        float2 v = cbuf[i];
        cbuf[i] = make_float2(v.x * H, v.y * H);
    }
    __syncthreads();

    for (int half = 1; half <= N_ / 2; half <<= 1) {
        const float astep = cpi / (float)half;
        #pragma unroll
        for (int u = 0; u < 8; ++u) {
            int g  = t + u * 512;
            int jj = g & (half - 1);
            int i0 = ((g - jj) << 1) + jj;
            int i1 = i0 + half;
            float ss, cc;
            __sincosf(astep * (float)jj, &ss, &cc);
            float2 vv = cbuf[i1];
            float tr  = vv.x * cc - vv.y * ss;
            float tii = vv.x * ss + vv.y * cc;
            float2 uv = cbuf[i0];
            cbuf[i0] = make_float2(uv.x + tr,  uv.y + tii);
            cbuf[i1] = make_float2(uv.x - tr,  uv.y - tii);
        }
        __syncthreads();
    }

    const float inv = 1.0f / (float)N_;
    for (int i = t; i < N_; i += 512) row[i] = cbuf[i].x * inv;
}

// ---------------------------------------------------------------------------
// K5: t[b,n,r] = sum_k y[b,k,n] * U[k,r];  out = x + t @ G^T + bu
// ---------------------------------------------------------------------------
__global__ void out_kernel(const float* __restrict__ x,
                           const float* __restrict__ y_t,
                           const float* __restrict__ U,
                           const float* __restrict__ G,
                           const float* __restrict__ bu,
                           float*       __restrict__ out) {
    __shared__ float ttile[64][R_];
    const int blk = blockIdx.x;          // 2048
    const int b   = blk >> 7;
    const int n0  = (blk & 127) << 6;
    const int t   = threadIdx.x;

    {
        const int nl = t >> 2, r = t & 3;
        const float* yb = y_t + (size_t)b * BN_ * N_ + n0 + nl;
        float s = 0.0f;
        #pragma unroll
        for (int kk = 0; kk < BN_; ++kk) s += yb[(size_t)kk * N_] * U[kk * R_ + r];
        ttile[nl][r] = s;
    }
    __syncthreads();

    float4 g = *(const float4*)(G + t * 4);
    float bv = bu[t];
    const float* xb = x   + ((size_t)b * N_ + n0) * D_;
    float*       ob = out + ((size_t)b * N_ + n0) * D_;
    for (int nl = 0; nl < 64; ++nl) {
        float t0 = ttile[nl][0], t1 = ttile[nl][1];
        float t2 = ttile[nl][2], t3 = ttile[nl][3];
        ob[nl * D_ + t] = xb[nl * D_ + t]
                        + t0 * g.x + t1 * g.y + t2 * g.z + t3 * g.w + bv;
    }
}

// ---------------------------------------------------------------------------
extern "C" void kernel_launch(void* const* d_in, const int* in_sizes, int n_in,
                              void* d_out, int out_size, void* d_ws, size_t ws_size,
                              hipStream_t stream) {
    const float* x       = (const float*)d_in[0];
    const float* coords  = (const float*)d_in[1];
    const float* Wd      = (const float*)d_in[2];
    const float* bd      = (const float*)d_in[3];
    const float* U       = (const float*)d_in[4];
    const float* V       = (const float*)d_in[5];
    const float* logit_d = (const float*)d_in[6];
    const float* Wu      = (const float*)d_in[7];
    const float* bu      = (const float*)d_in[8];
    float* out = (float*)d_out;

    char* ws = (char*)d_ws;
    int*                order = (int*)ws;                            // 512 KB
    unsigned long long* keys  = (unsigned long long*)(ws + 512*1024); // 1 MB
    float*              G     = (float*)(ws + 1536 * 1024);          // 4 KB
    float*              zy    = (float*)(ws + 2048 * 1024);          // 16 MB

    sort1_kernel<<<dim3(2 * B_), dim3(1024), 0, stream>>>(coords, keys);
    sort2_kernel<<<dim3(B_), dim3(1024), 0, stream>>>(keys, order);
    zgemm_kernel<<<dim3(B_ * 128), dim3(256), 0, stream>>>(x, coords, Wd, bd, order, zy);
    g_kernel<<<dim3(1), dim3(256), 0, stream>>>(Wu, V, G);
    fft_filter_kernel<<<dim3(B_ * BN_), dim3(512), 64 * 1024, stream>>>(zy, logit_d);
    out_kernel<<<dim3(B_ * 128), dim3(256), 0, stream>>>(x, zy, U, G, bu, out);
}

// Round 5
// 164.097 us; speedup vs baseline: 4.1026x; 1.1444x over previous
//
#include <hip/hip_runtime.h>
#include <math.h>

#define B_    16
#define N_    8192
#define D_    256
#define BN_   32
#define R_    4
#define LOGN  13

typedef float  f32x4  __attribute__((ext_vector_type(4)));
typedef short  s16x8  __attribute__((ext_vector_type(8)));

// ---------------------------------------------------------------------------
// Morton helpers (exact replica of reference bit-interleave)
// ---------------------------------------------------------------------------
__device__ __forceinline__ unsigned long long interleave3(unsigned long long v) {
    v = v & 2097151ULL;
    v = v | (v << 32);
    v = v & 8725724278095871ULL;
    v = v | ((v << 16) & 8725728556220671ULL);
    v = v | ((v << 8)  & 282506020581391ULL);
    v = v | ((v << 4)  & 294878547030211ULL);
    v = v | ((v << 2)  & 321685687669321ULL);
    return v;
}

__device__ __forceinline__ long long quant10(float c) {
    long long v = (long long)(c * 1023.0f);
    v = v < 0 ? 0 : (v > 1023 ? 1023 : v);
    return v;
}

__device__ __forceinline__ unsigned short f2bf(float f) {
    unsigned u = __float_as_uint(f);
    u = (u + 0x7FFF + ((u >> 16) & 1)) >> 16;   // RNE
    return (unsigned short)u;
}

// ---------------------------------------------------------------------------
// S1: 32 blocks (b, half). Bitonic phases size=2..4096 on 4096 keys in LDS.
// ---------------------------------------------------------------------------
__global__ __launch_bounds__(1024)
void sort1_kernel(const float* __restrict__ coords, unsigned long long* __restrict__ keys) {
    __shared__ unsigned long long skey[4096];    // 32 KB
    const int b = blockIdx.x >> 1;
    const int h = blockIdx.x & 1;
    const int t = threadIdx.x;
    const int gbase = h * 4096;

    for (int i = t; i < 4096; i += 1024) {
        const int gi = gbase + i;
        const float* c = coords + ((size_t)b * N_ + gi) * 3;
        unsigned long long mx = interleave3((unsigned long long)quant10(c[0]));
        unsigned long long my = interleave3((unsigned long long)quant10(c[1]));
        unsigned long long mz = interleave3((unsigned long long)quant10(c[2]));
        unsigned long long m = mx | (my << 1) | (mz << 2);
        skey[i] = (m << LOGN) | (unsigned long long)gi;
    }
    __syncthreads();

    for (int size = 2; size <= 4096; size <<= 1) {
        for (int s = size >> 1; s > 0; s >>= 1) {
            int i_[2];
            unsigned long long a_[2], b_[2];
            #pragma unroll
            for (int u = 0; u < 2; ++u) {
                int p  = t + u * 1024;
                int jj = p & (s - 1);
                int i  = ((p - jj) << 1) + jj;
                i_[u] = i; a_[u] = skey[i]; b_[u] = skey[i + s];
            }
            #pragma unroll
            for (int u = 0; u < 2; ++u) {
                bool up = (((gbase + i_[u]) & size) == 0);
                unsigned long long lo = a_[u] < b_[u] ? a_[u] : b_[u];
                unsigned long long hi = a_[u] < b_[u] ? b_[u] : a_[u];
                skey[i_[u]]     = up ? lo : hi;
                skey[i_[u] + s] = up ? hi : lo;
            }
            __syncthreads();
        }
    }
    for (int i = t; i < 4096; i += 1024)
        keys[(size_t)b * N_ + gbase + i] = skey[i];
}

// ---------------------------------------------------------------------------
// S2: 16 blocks. Final merge phase (size=8192, ascending).
// Emits order[b][p] = natural index of the p-th smallest key.
// ---------------------------------------------------------------------------
__global__ __launch_bounds__(1024)
void sort2_kernel(const unsigned long long* __restrict__ keys, int* __restrict__ order) {
    __shared__ unsigned long long skey[N_];      // 64 KB
    const int b = blockIdx.x;
    const int t = threadIdx.x;

    for (int i = t; i < N_; i += 1024) skey[i] = keys[(size_t)b * N_ + i];
    __syncthreads();

    for (int s = 4096; s > 0; s >>= 1) {
        int i_[4];
        unsigned long long a_[4], b_[4];
        #pragma unroll
        for (int u = 0; u < 4; ++u) {
            int p  = t + u * 1024;
            int jj = p & (s - 1);
            int i  = ((p - jj) << 1) + jj;
            i_[u] = i; a_[u] = skey[i]; b_[u] = skey[i + s];
        }
        #pragma unroll
        for (int u = 0; u < 4; ++u) {
            unsigned long long lo = a_[u] < b_[u] ? a_[u] : b_[u];
            unsigned long long hi = a_[u] < b_[u] ? b_[u] : a_[u];
            skey[i_[u]]     = lo;
            skey[i_[u] + s] = hi;
        }
        __syncthreads();
    }
    for (int i = t; i < N_; i += 1024)
        order[b * N_ + i] = (int)(skey[i] & (unsigned long long)(N_ - 1));
}

// ---------------------------------------------------------------------------
// K2 (MFMA): processes 64 consecutive SORTED slots p; gathers x rows via
// order[p], radius from coords[b][p], z written at consecutive p.
// ---------------------------------------------------------------------------
__global__ __launch_bounds__(256)
void zgemm_kernel(const float* __restrict__ x,
                  const float* __restrict__ coords,
                  const float* __restrict__ Wd,
                  const float* __restrict__ bd,
                  const int*   __restrict__ order,
                  float*       __restrict__ z_t) {
    __shared__ char xlds[64 * 256 * 2];    // 32 KB
    __shared__ char wdlds[32 * 256 * 2];   // 16 KB
    __shared__ float sWdLast[BN_];
    __shared__ float sbd[BN_];

    const int blk = blockIdx.x;           // 2048 = 16 * 128
    const int b   = blk >> 7;
    const int p0  = (blk & 127) << 6;
    const int t   = threadIdx.x;
    const int w   = t >> 6;
    const int l   = t & 63;

    for (int rr_ = 0; rr_ < 16; ++rr_) {
        const int row = rr_ * 4 + w;
        const int od  = order[b * N_ + p0 + row];
        const float4 v = *(const float4*)(x + ((size_t)(b * N_ + od)) * D_ + l * 4);
        unsigned off = (row << 9) + (l << 3);
        off ^= (row & 7) << 4;
        ushort4 pk = make_ushort4(f2bf(v.x), f2bf(v.y), f2bf(v.z), f2bf(v.w));
        *(ushort4*)(xlds + off) = pk;
    }
    for (int rr_ = 0; rr_ < 8; ++rr_) {
        const int row = rr_ * 4 + w;
        const float4 v = *(const float4*)(Wd + (size_t)row * 257 + l * 4);
        unsigned off = (row << 9) + (l << 3);
        off ^= (row & 7) << 4;
        ushort4 pk = make_ushort4(f2bf(v.x), f2bf(v.y), f2bf(v.z), f2bf(v.w));
        *(ushort4*)(wdlds + off) = pk;
    }
    if (t < BN_) { sWdLast[t] = Wd[(size_t)t * 257 + 256]; sbd[t] = bd[t]; }
    __syncthreads();

    const int lg = l >> 4;
    const int lm = l & 15;
    f32x4 acc0 = {0.f, 0.f, 0.f, 0.f};
    f32x4 acc1 = {0.f, 0.f, 0.f, 0.f};
    const int xr = w * 16 + lm;
    #pragma unroll
    for (int kc = 0; kc < 8; ++kc) {
        const unsigned doff = kc * 64 + lg * 16;
        s16x8 bfr = *(const s16x8*)(xlds  + ((((unsigned)xr << 9) + doff) ^ ((xr & 7) << 4)));
        s16x8 a0  = *(const s16x8*)(wdlds + ((((unsigned)lm << 9) + doff) ^ ((lm & 7) << 4)));
        s16x8 a1  = *(const s16x8*)(wdlds + ((((unsigned)(16 + lm) << 9) + doff) ^ ((lm & 7) << 4)));
        acc0 = __builtin_amdgcn_mfma_f32_16x16x32_bf16(a0, bfr, acc0, 0, 0, 0);
        acc1 = __builtin_amdgcn_mfma_f32_16x16x32_bf16(a1, bfr, acc1, 0, 0, 0);
    }

    const int p = p0 + w * 16 + lm;
    const float* c = coords + ((size_t)(b * N_ + p)) * 3;
    const float rr = sqrtf(c[0] * c[0] + c[1] * c[1] + c[2] * c[2]);
    float* zb = z_t + (size_t)b * BN_ * N_ + p;
    #pragma unroll
    for (int j = 0; j < 4; ++j) {
        const int kk = lg * 4 + j;
        float v0 = acc0[j] + rr * sWdLast[kk]      + sbd[kk];
        float v1 = acc1[j] + rr * sWdLast[kk + 16] + sbd[kk + 16];
        zb[(size_t)kk * N_]        = fmaxf(v0, 0.0f);
        zb[(size_t)(kk + 16) * N_] = fmaxf(v1, 0.0f);
    }
}

// ---------------------------------------------------------------------------
// K3: tiny precompute G = Wu @ V   [256,4]
// ---------------------------------------------------------------------------
__global__ void g_kernel(const float* __restrict__ Wu, const float* __restrict__ V,
                         float* __restrict__ G) {
    const int d = threadIdx.x;   // 256
    for (int r = 0; r < R_; ++r) {
        float s = 0.0f;
        for (int kk = 0; kk < BN_; ++kk) s += Wu[d * BN_ + kk] * V[kk * R_ + r];
        G[d * R_ + r] = s;
    }
}

// ---------------------------------------------------------------------------
// K4: per-(b,k) length-8192 FFT -> H -> IFFT -> real, in place.
// Radix-2 dataflow with TWO stages fused per LDS pass (closed 4-element
// groups in registers). Global load fused into first forward pass; H +
// fwd h=1 + inv h=1,2 fused into one middle pass; 1/N + global store fused
// into the last inverse pass. 13 LDS passes total (was ~29).
// ---------------------------------------------------------------------------
__device__ __forceinline__ float2 cmul(float2 a, float2 b) {
    return make_float2(a.x * b.x - a.y * b.y, a.x * b.y + a.y * b.x);
}

__global__ __launch_bounds__(512)
void fft_filter_kernel(float* __restrict__ zy,
                       const float* __restrict__ logit_d) {
    extern __shared__ float2 cbuf[];   // 64 KB

    const int bk = blockIdx.x;     // 512
    const int b  = bk >> 5;
    const int k  = bk & 31;
    const int t  = threadIdx.x;

    float* row = zy + (size_t)(b * BN_ + k) * N_;

    float d = logit_d[k];
    d = fminf(fmaxf(d, -10.0f), 10.0f);

    const float cpi  = 3.14159265358979323846f;
    const float c2pi = 6.28318530717958647692f;

    // ---- F1: fused forward h=4096,2048; input from GLOBAL (imag = 0) ----
    {
        const int h = 4096;
        #pragma unroll
        for (int u = 0; u < 4; ++u) {
            const int q  = t + u * 512;        // 2048 groups; blk==0, i0=q
            const int i0 = q;
            float r0 = row[i0];
            float r1 = row[i0 + h / 2];
            float r2 = row[i0 + h];
            float r3 = row[i0 + 3 * h / 2];
            float sA, cA;
            __sincosf(-cpi * (float)i0 / (float)h, &sA, &cA);
            const float cB = 2.0f * cA * cA - 1.0f, sB = 2.0f * sA * cA;
            // stage A (real inputs)
            float a0 = r0 + r2, a1 = r1 + r3;                      // i0, i0+h/2 (real)
            float2 b0 = make_float2((r0 - r2) * cA, (r0 - r2) * sA);       // tw (cA,sA)
            float2 b1 = make_float2((r1 - r3) * sA, -(r1 - r3) * cA);      // tw (sA,-cA)
            // stage B
            cbuf[i0]             = make_float2(a0 + a1, 0.0f);
            cbuf[i0 + h / 2]     = make_float2((a0 - a1) * cB, (a0 - a1) * sB);
            float2 s0 = make_float2(b0.x + b1.x, b0.y + b1.y);
            float2 s1 = make_float2(b0.x - b1.x, b0.y - b1.y);
            cbuf[i0 + h]         = s0;
            cbuf[i0 + 3 * h / 2] = cmul(s1, make_float2(cB, sB));
        }
        __syncthreads();
    }

    // ---- F2..F6: fused forward (h, h/2) for h = 1024,256,64,16,4 ----
    #pragma unroll
    for (int h = 1024; h >= 4; h >>= 2) {
        const int hh = h >> 1;
        #pragma unroll
        for (int u = 0; u < 4; ++u) {
            const int q   = t + u * 512;
            const int jj  = q & (hh - 1);
            const int i0  = ((q - jj) << 2) + jj;   // blk*2h + jj
            float2 c0 = cbuf[i0];
            float2 c1 = cbuf[i0 + hh];
            float2 c2 = cbuf[i0 + h];
            float2 c3 = cbuf[i0 + h + hh];
            float sA, cA;
            __sincosf(-cpi * (float)jj / (float)h, &sA, &cA);
            const float2 twA1 = make_float2(cA, sA);
            const float2 twA2 = make_float2(sA, -cA);
            const float2 twB  = make_float2(2.0f * cA * cA - 1.0f, 2.0f * sA * cA);
            // stage A
            float2 a0 = make_float2(c0.x + c2.x, c0.y + c2.y);
            float2 a1 = make_float2(c1.x + c3.x, c1.y + c3.y);
            float2 b0 = cmul(make_float2(c0.x - c2.x, c0.y - c2.y), twA1);
            float2 b1 = cmul(make_float2(c1.x - c3.x, c1.y - c3.y), twA2);
            // stage B
            cbuf[i0]          = make_float2(a0.x + a1.x, a0.y + a1.y);
            cbuf[i0 + hh]     = cmul(make_float2(a0.x - a1.x, a0.y - a1.y), twB);
            cbuf[i0 + h]      = make_float2(b0.x + b1.x, b0.y + b1.y);
            cbuf[i0 + h + hh] = cmul(make_float2(b0.x - b1.x, b0.y - b1.y), twB);
        }
        __syncthreads();
    }

    // ---- M: forward h=1  +  H (bit-reversed index)  +  inverse h=1,2 ----
    {
        #pragma unroll
        for (int u = 0; u < 4; ++u) {
            const int q  = t + u * 512;
            const int i0 = q << 2;
            float2 c0 = cbuf[i0], c1 = cbuf[i0 + 1], c2 = cbuf[i0 + 2], c3 = cbuf[i0 + 3];
            // forward h=1 (twiddle 1)
            float2 e0 = make_float2(c0.x + c1.x, c0.y + c1.y);
            float2 e1 = make_float2(c0.x - c1.x, c0.y - c1.y);
            float2 e2 = make_float2(c2.x + c3.x, c2.y + c3.y);
            float2 e3 = make_float2(c2.x - c3.x, c2.y - c3.y);
            // H at bit-reversed positions
            #pragma unroll
            for (int j = 0; j < 4; ++j) {
                float2* e = (j == 0) ? &e0 : (j == 1) ? &e1 : (j == 2) ? &e2 : &e3;
                int kk = (int)(__brev((unsigned)(i0 + j)) >> (32 - LOGN));
                float w = c2pi * (float)kk / (float)(N_ - 1);
                float H = expf(-w * d);
                e->x *= H; e->y *= H;
            }
            // inverse h=1 (twiddle 1)
            float2 f0 = make_float2(e0.x + e1.x, e0.y + e1.y);
            float2 f1 = make_float2(e0.x - e1.x, e0.y - e1.y);
            float2 f2 = make_float2(e2.x + e3.x, e2.y + e3.y);
            float2 f3 = make_float2(e2.x - e3.x, e2.y - e3.y);
            // inverse h=2: (i0,i0+2) tw=1 ; (i0+1,i0+3) tw=+i
            cbuf[i0]     = make_float2(f0.x + f2.x, f0.y + f2.y);
            cbuf[i0 + 2] = make_float2(f0.x - f2.x, f0.y - f2.y);
            float2 tt = make_float2(-f3.y, f3.x);
            cbuf[i0 + 1] = make_float2(f1.x + tt.x, f1.y + tt.y);
            cbuf[i0 + 3] = make_float2(f1.x - tt.x, f1.y - tt.y);
        }
        __syncthreads();
    }

    // ---- I2..I6: fused inverse (h, 2h) for h = 4,16,64,256,1024 ----
    #pragma unroll
    for (int h = 4; h <= 1024; h <<= 2) {
        #pragma unroll
        for (int u = 0; u < 4; ++u) {
            const int q  = t + u * 512;
            const int jj = q & (h - 1);
            const int i0 = ((q - jj) << 2) + jj;    // blk*4h + jj
            float2 c0 = cbuf[i0];
            float2 c1 = cbuf[i0 + h];
            float2 c2 = cbuf[i0 + 2 * h];
            float2 c3 = cbuf[i0 + 3 * h];
            float sa, ca;
            __sincosf(cpi * (float)jj / (float)(2 * h), &sa, &ca);
            const float2 tw1 = make_float2(2.0f * ca * ca - 1.0f, 2.0f * sa * ca); // angle 2a
            const float2 tw2a = make_float2(ca, sa);         // angle a
            const float2 tw2b = make_float2(-sa, ca);        // angle a + pi/2
            // stage 1 (half=h), DIT
            float2 t0 = cmul(c1, tw1);
            float2 a0 = make_float2(c0.x + t0.x, c0.y + t0.y);
            float2 a1 = make_float2(c0.x - t0.x, c0.y - t0.y);
            float2 t1 = cmul(c3, tw1);
            float2 b0 = make_float2(c2.x + t1.x, c2.y + t1.y);
            float2 b1 = make_float2(c2.x - t1.x, c2.y - t1.y);
            // stage 2 (half=2h)
            float2 t2 = cmul(b0, tw2a);
            cbuf[i0]         = make_float2(a0.x + t2.x, a0.y + t2.y);
            cbuf[i0 + 2 * h] = make_float2(a0.x - t2.x, a0.y - t2.y);
            float2 t3 = cmul(b1, tw2b);
            cbuf[i0 + h]     = make_float2(a1.x + t3.x, a1.y + t3.y);
            cbuf[i0 + 3 * h] = make_float2(a1.x - t3.x, a1.y - t3.y);
        }
        __syncthreads();
    }

    // ---- I7: inverse h=4096 single stage, scaled REAL write to global ----
    {
        const int h = 4096;
        const float inv = 1.0f / (float)N_;
        #pragma unroll
        for (int u = 0; u < 8; ++u) {
            const int g = t + u * 512;          // 4096 pairs
            float sa, ca;
            __sincosf(cpi * (float)g / (float)h, &sa, &ca);
            float2 c0 = cbuf[g];
            float2 c1 = cbuf[g + h];
            float tx = c1.x * ca - c1.y * sa;
            row[g]     = (c0.x + tx) * inv;
            row[g + h] = (c0.x - tx) * inv;
        }
    }
}

// ---------------------------------------------------------------------------
// K5: t[b,n,r] = sum_k y[b,k,n] * U[k,r];  out = x + t @ G^T + bu
// ---------------------------------------------------------------------------
__global__ void out_kernel(const float* __restrict__ x,
                           const float* __restrict__ y_t,
                           const float* __restrict__ U,
                           const float* __restrict__ G,
                           const float* __restrict__ bu,
                           float*       __restrict__ out) {
    __shared__ float ttile[64][R_];
    const int blk = blockIdx.x;          // 2048
    const int b   = blk >> 7;
    const int n0  = (blk & 127) << 6;
    const int t   = threadIdx.x;

    {
        const int nl = t >> 2, r = t & 3;
        const float* yb = y_t + (size_t)b * BN_ * N_ + n0 + nl;
        float s = 0.0f;
        #pragma unroll
        for (int kk = 0; kk < BN_; ++kk) s += yb[(size_t)kk * N_] * U[kk * R_ + r];
        ttile[nl][r] = s;
    }
    __syncthreads();

    float4 g = *(const float4*)(G + t * 4);
    float bv = bu[t];
    const float* xb = x   + ((size_t)b * N_ + n0) * D_;
    float*       ob = out + ((size_t)b * N_ + n0) * D_;
    for (int nl = 0; nl < 64; ++nl) {
        float t0 = ttile[nl][0], t1 = ttile[nl][1];
        float t2 = ttile[nl][2], t3 = ttile[nl][3];
        ob[nl * D_ + t] = xb[nl * D_ + t]
                        + t0 * g.x + t1 * g.y + t2 * g.z + t3 * g.w + bv;
    }
}

// ---------------------------------------------------------------------------
extern "C" void kernel_launch(void* const* d_in, const int* in_sizes, int n_in,
                              void* d_out, int out_size, void* d_ws, size_t ws_size,
                              hipStream_t stream) {
    const float* x       = (const float*)d_in[0];
    const float* coords  = (const float*)d_in[1];
    const float* Wd      = (const float*)d_in[2];
    const float* bd      = (const float*)d_in[3];
    const float* U       = (const float*)d_in[4];
    const float* V       = (const float*)d_in[5];
    const float* logit_d = (const float*)d_in[6];
    const float* Wu      = (const float*)d_in[7];
    const float* bu      = (const float*)d_in[8];
    float* out = (float*)d_out;

    char* ws = (char*)d_ws;
    int*                order = (int*)ws;                            // 512 KB
    unsigned long long* keys  = (unsigned long long*)(ws + 512*1024); // 1 MB
    float*              G     = (float*)(ws + 1536 * 1024);          // 4 KB
    float*              zy    = (float*)(ws + 2048 * 1024);          // 16 MB

    sort1_kernel<<<dim3(2 * B_), dim3(1024), 0, stream>>>(coords, keys);
    sort2_kernel<<<dim3(B_), dim3(1024), 0, stream>>>(keys, order);
    zgemm_kernel<<<dim3(B_ * 128), dim3(256), 0, stream>>>(x, coords, Wd, bd, order, zy);
    g_kernel<<<dim3(1), dim3(256), 0, stream>>>(Wu, V, G);
    fft_filter_kernel<<<dim3(B_ * BN_), dim3(512), 64 * 1024, stream>>>(zy, logit_d);
    out_kernel<<<dim3(B_ * 128), dim3(256), 0, stream>>>(x, zy, U, G, bu, out);
}